// Round 8
// baseline (3309.566 us; speedup 1.0000x reference)
//
#include <hip/hip_runtime.h>

typedef __bf16 bf16_t;
typedef bf16_t bf16x8 __attribute__((ext_vector_type(8)));
typedef bf16_t bf16x4 __attribute__((ext_vector_type(4)));
typedef float f32x4 __attribute__((ext_vector_type(4)));

#define B_SZ 256
#define T_SZ 512
#define H_SZ 256
#define SCOPE_AGENT __HIP_MEMORY_SCOPE_AGENT
#define SENT32 0x7FC17FC1u   // two bf16 NaNs; produced h is always finite

__device__ __forceinline__ float sigm(float x) { return 1.f / (1.f + __expf(-x)); }
__device__ __forceinline__ float tanhx(float x) {
  x = fminf(fmaxf(x, -15.f), 15.f);
  float e = __expf(-2.f * x);
  return (1.f - e) / (1.f + e);
}
__device__ __forceinline__ uint32_t pack_bf16x2(float a, float b) {
  union { bf16_t h[2]; uint32_t u; } v;
  v.h[0] = (bf16_t)a; v.h[1] = (bf16_t)b; return v.u;
}
__device__ __forceinline__ uint32_t bf16bits(float a) {
  union { bf16_t h; uint16_t u; } v; v.h = (bf16_t)a; return (uint32_t)v.u;
}
__device__ __forceinline__ void st32_agent(uint32_t* p, uint32_t v) {
  __hip_atomic_store(p, v, __ATOMIC_RELAXED, SCOPE_AGENT);
}
__device__ __forceinline__ uint64_t ld64_agent(const uint64_t* p) {
  return __hip_atomic_load(p, __ATOMIC_RELAXED, SCOPE_AGENT);
}
__device__ __forceinline__ bool okv(uint64_t v) {
  return ((uint32_t)v != SENT32) & ((uint32_t)(v >> 32) != SENT32);
}
#define MFMA(a, b, c) __builtin_amdgcn_mfma_f32_16x16x32_bf16((a), (b), (c), 0, 0, 0)

// ---------------------------------------------------------------------------
// Layer 0 scan — BARRIER-FREE. 128 blocks = 4 ct x (2 dir x 16 bt), 256 thr
// (4 waves). Wave owns 16 h-cols x ALL 4 GATES (4 N-tiles):
//  - 4 gate accs share one C/D layout -> i/f/g/o combine is pure-register
//  - h_prev A-frag (A[m=l15][k=quad*8+j]) is polled DIRECTLY from global
//    into registers -> no LDS stage, no __syncthreads anywhere
//  - publish: shfl_xor pack to u32, even lanes store agent-scope
// Weights (wih + whh hi/lo) register-resident (~290 VGPR) -> 1 wave/SIMD
// (launch_bounds(256,1)); 128 blocks = 1 block/CU, all resident.
// Flag-in-data on h0[t] (NaN sentinel), relaxed agent ops, no fences.
// ---------------------------------------------------------------------------
__global__ __launch_bounds__(256, 1) void l0_scan(
    const bf16_t* __restrict__ xbf,
    const bf16_t* __restrict__ wih_f, const bf16_t* __restrict__ whhhi_f,
    const bf16_t* __restrict__ whhlo_f, const float* __restrict__ bias_f,
    const bf16_t* __restrict__ wih_b, const bf16_t* __restrict__ whhhi_b,
    const bf16_t* __restrict__ whhlo_b, const float* __restrict__ bias_b,
    bf16_t* __restrict__ h0) {
  const int id = blockIdx.x;
  const int ct = id >> 5;            // 0..3 (XCD-locality swizzle)
  const int g  = id & 31;
  const int dir = g >> 4, bt = g & 15;
  const bf16_t* __restrict__ wih  = dir ? wih_b : wih_f;
  const bf16_t* __restrict__ whhh = dir ? whhhi_b : whhhi_f;
  const bf16_t* __restrict__ whhl = dir ? whhlo_b : whhlo_f;
  const float*  __restrict__ bias = dir ? bias_b : bias_f;

  const int tid = threadIdx.x;
  const int lane = tid & 63, wv = tid >> 6, l15 = lane & 15, quad = lane >> 4;
  const int b0 = bt * 16;
  const int jc = ct * 64 + wv * 16 + l15;   // h-col this lane owns (B n / D col)

  // ---- register-resident weights: 4 gates x own col, all K ----
  bf16x8 wfi[4][2], wfh[4][8], wfl[4][8];
#pragma unroll
  for (int g4 = 0; g4 < 4; ++g4) {
    const int row = g4 * H_SZ + jc;
#pragma unroll
    for (int kt = 0; kt < 2; ++kt)
      wfi[g4][kt] = *(const bf16x8*)(wih + (size_t)row * 64 + kt * 32 + quad * 8);
#pragma unroll
    for (int kt = 0; kt < 8; ++kt) {
      wfh[g4][kt] = *(const bf16x8*)(whhh + (size_t)row * H_SZ + kt * 32 + quad * 8);
      wfl[g4][kt] = *(const bf16x8*)(whhl + (size_t)row * H_SZ + kt * 32 + quad * 8);
    }
  }
  float bia4[4];
#pragma unroll
  for (int g4 = 0; g4 < 4; ++g4) bia4[g4] = bias[g4 * H_SZ + jc];

  f32x4 c4 = {0.f, 0.f, 0.f, 0.f};
  const bf16_t* xrow = xbf + (size_t)(b0 + l15) * T_SZ * 64;
  const int jc0 = ct * 64 + wv * 16 + (l15 & ~1);   // even-col store address
  const bool evn = (l15 & 1) == 0;

  for (int s = 0; s < T_SZ; ++s) {
    const int t = dir ? (T_SZ - 1 - s) : s;
    // ---- input projection (independent of recurrence) ----
    f32x4 acc[4] = {{0,0,0,0},{0,0,0,0},{0,0,0,0},{0,0,0,0}};
#pragma unroll
    for (int kt = 0; kt < 2; ++kt) {
      bf16x8 xa = *(const bf16x8*)(xrow + t * 64 + kt * 32 + quad * 8);
#pragma unroll
      for (int g4 = 0; g4 < 4; ++g4) acc[g4] = MFMA(xa, wfi[g4][kt], acc[g4]);
    }
    if (s > 0) {
      // ---- poll h_{s-1} A-fragment DIRECTLY into registers ----
      const int tp = dir ? (t + 1) : (t - 1);
      const uint64_t* hsrc =
          (const uint64_t*)(h0 + ((size_t)tp * B_SZ + b0 + l15) * 512 + dir * H_SZ);
      uint64_t v[16];
      bool all;
      do {
        all = true;
#pragma unroll
        for (int kt = 0; kt < 8; ++kt) {
          v[2 * kt]     = ld64_agent(hsrc + kt * 8 + quad * 2);
          v[2 * kt + 1] = ld64_agent(hsrc + kt * 8 + quad * 2 + 1);
          all = all && okv(v[2 * kt]) && okv(v[2 * kt + 1]);
        }
      } while (!all);
      // ---- recurrent MFMAs (weights + A-frags all in registers) ----
#pragma unroll
      for (int kt = 0; kt < 8; ++kt) {
        union { uint64_t u[2]; bf16x8 h; } ha;
        ha.u[0] = v[2 * kt]; ha.u[1] = v[2 * kt + 1];
#pragma unroll
        for (int g4 = 0; g4 < 4; ++g4) {
          acc[g4] = MFMA(ha.h, wfh[g4][kt], acc[g4]);
          acc[g4] = MFMA(ha.h, wfl[g4][kt], acc[g4]);
        }
      }
    }
    // ---- pure-register epilogue + publish ----
#pragma unroll
    for (int r = 0; r < 4; ++r) {
      const int row = quad * 4 + r;
      float iv = sigm(acc[0][r] + bia4[0]);
      float fv = sigm(acc[1][r] + bia4[1]);
      float gv = tanhx(acc[2][r] + bia4[2]);
      float ov = sigm(acc[3][r] + bia4[3]);
      float cn = fv * c4[r] + iv * gv;
      c4[r] = cn;
      uint32_t bits = bf16bits(ov * tanhx(cn));
      uint32_t partner = (uint32_t)__shfl_xor((int)bits, 1);
      if (evn) {
        uint32_t pk = (bits & 0xffffu) | (partner << 16);
        st32_agent((uint32_t*)(h0 + ((size_t)t * B_SZ + b0 + row) * 512 + dir * H_SZ + jc0),
                   pk);
      }
    }
  }
}

// ---------------------------------------------------------------------------
// Layer 1 forward scan. 128 blocks (ct = id>>4 -> siblings share an XCD),
// 512 threads (8 waves). Prefetch loads at loop top, ds_write deferred past
// the poll. Own-slice shortcut: epilogue writes own 32 cols into next
// step's LDS stage; poll covers 7/8 of the tile.
// ---------------------------------------------------------------------------
__global__ __launch_bounds__(512, 2) void l1_scan(
    const bf16_t* __restrict__ h0,
    const bf16_t* __restrict__ wih, const bf16_t* __restrict__ whhh,
    const bf16_t* __restrict__ whhl, const float* __restrict__ bias,
    bf16_t* __restrict__ h1f, bf16_t* __restrict__ hg1) {
  const int id = blockIdx.x;
  const int ct = id >> 4, bt = id & 15;       // XCD-locality swizzle
  bf16_t* hgs = hg1 + (size_t)bt * T_SZ * 4096;   // [s][16][256]

  const int tid = threadIdx.x;
  const int lane = tid & 63, wv = tid >> 6, l15 = lane & 15, quad = lane >> 4;
  const int b0 = bt * 16;

  __shared__ bf16_t ibl[2][16][520];
  __shared__ bf16_t hbl[16][264];
  __shared__ float  gl[16][132];

  const int gc = wv * 16 + l15;
  const int row = (gc >> 5) * H_SZ + ct * 32 + (gc & 31);
  bf16x8 wfi[16], wfh[8], wfl[8];
#pragma unroll
  for (int kt = 0; kt < 16; ++kt)
    wfi[kt] = *(const bf16x8*)(wih + (size_t)row * 512 + kt * 32 + quad * 8);
#pragma unroll
  for (int kt = 0; kt < 8; ++kt) {
    wfh[kt] = *(const bf16x8*)(whhh + (size_t)row * H_SZ + kt * 32 + quad * 8);
    wfl[kt] = *(const bf16x8*)(whhl + (size_t)row * H_SZ + kt * 32 + quad * 8);
  }
  const int et = tid & 255;
  const int erow = et >> 4, ecol = 2 * (et & 15);
  const int gj = ct * 32 + ecol;
  float bia[4][2];
#pragma unroll
  for (int g = 0; g < 4; ++g) {
    bia[g][0] = bias[g * H_SZ + gj];
    bia[g][1] = bias[g * H_SZ + gj + 1];
  }
  float2 c2 = {0.f, 0.f};
  const int prow = tid >> 5, pcq = (tid & 31) * 2;   // poll ownership
  const bool own = ((tid & 31) >> 2) == ct;          // own-slice threads skip
  const int fr = tid >> 5, fcc = (tid & 31) * 16;    // prefetch ownership

  // stage ibl[0] <- h0[t=0]
  {
    const bf16_t* src = h0 + ((size_t)(b0 + fr)) * 512 + fcc;
    *(bf16x8*)&ibl[0][fr][fcc]     = *(const bf16x8*)(src);
    *(bf16x8*)&ibl[0][fr][fcc + 8] = *(const bf16x8*)(src + 8);
  }
  __syncthreads();

  for (int s = 0; s < T_SZ; ++s) {
    const int cur = s & 1, nxt = cur ^ 1;
    // issue next-tile global loads NOW; ds_write deferred past the poll
    bf16x8 pf0, pf1;
    if (s + 1 < T_SZ) {
      const bf16_t* src = h0 + ((size_t)(s + 1) * B_SZ + b0 + fr) * 512 + fcc;
      pf0 = *(const bf16x8*)(src);
      pf1 = *(const bf16x8*)(src + 8);
    }
    // ---- input projection before poll ----
    f32x4 acc = {0.f, 0.f, 0.f, 0.f};
#pragma unroll
    for (int kt = 0; kt < 16; ++kt) {
      bf16x8 a = *(const bf16x8*)&ibl[cur][l15][kt * 32 + quad * 8];
      acc = MFMA(a, wfi[kt], acc);
    }
    if (s == 0) {
      for (int i = tid; i < 16 * 264 / 2; i += 512) ((uint32_t*)hbl)[i] = 0u;
    } else if (!own) {
      const uint64_t* src =
          (const uint64_t*)(hgs + (size_t)(s - 1) * 4096 + prow * H_SZ) + pcq;
      uint64_t v0, v1;
      for (;;) {
        v0 = ld64_agent(src); v1 = ld64_agent(src + 1);
        if (okv(v0) && okv(v1)) break;
      }
      uint64_t* dst = (uint64_t*)&hbl[prow][pcq * 4];
      dst[0] = v0; dst[1] = v1;
    }
    // deferred prefetch ds_write (load latency absorbed by the poll)
    if (s + 1 < T_SZ) {
      *(bf16x8*)&ibl[nxt][fr][fcc]     = pf0;
      *(bf16x8*)&ibl[nxt][fr][fcc + 8] = pf1;
    }
    __syncthreads();
#pragma unroll
    for (int kt = 0; kt < 8; ++kt) {
      bf16x8 ha = *(const bf16x8*)&hbl[l15][kt * 32 + quad * 8];
      acc = MFMA(ha, wfh[kt], acc);
      acc = MFMA(ha, wfl[kt], acc);
    }
#pragma unroll
    for (int r = 0; r < 4; ++r) gl[quad * 4 + r][wv * 16 + l15] = acc[r];
    __syncthreads();
    if (tid < 256) {
      float hv[2];
#pragma unroll
      for (int u = 0; u < 2; ++u) {
        float iv = sigm(gl[erow][0 * 32 + ecol + u] + bia[0][u]);
        float fv = sigm(gl[erow][1 * 32 + ecol + u] + bia[1][u]);
        float gv = tanhx(gl[erow][2 * 32 + ecol + u] + bia[2][u]);
        float ov = sigm(gl[erow][3 * 32 + ecol + u] + bia[3][u]);
        float cp = u ? c2.y : c2.x;
        float cn = fv * cp + iv * gv;
        if (u) c2.y = cn; else c2.x = cn;
        hv[u] = ov * tanhx(cn);
      }
      uint32_t pk = pack_bf16x2(hv[0], hv[1]);
      st32_agent((uint32_t*)(hgs + (size_t)s * 4096 + erow * H_SZ + gj), pk);
      *(uint32_t*)&hbl[erow][gj] = pk;   // own-slice shortcut
      if (s == T_SZ - 1)
        *(uint32_t*)(h1f + (size_t)(b0 + erow) * H_SZ + gj) = pk;
    }
  }
}

// ---------------------------------------------------------------------------
// Layer 1 reverse direction: output needs only t=T-1 = ONE step from zero
// state -> pure input projection + gate combine.
// ---------------------------------------------------------------------------
__global__ __launch_bounds__(256) void l1b_step(
    const bf16_t* __restrict__ h0, const bf16_t* __restrict__ wih_r,
    const float* __restrict__ bias_r, bf16_t* __restrict__ h1b) {
  const int bt = blockIdx.x >> 2, ct = blockIdx.x & 3;
  const int tid = threadIdx.x, lane = tid & 63, wv = tid >> 6;
  const int l15 = lane & 15, quad = lane >> 4;
  const int c0 = ct * 64 + wv * 16;
  const bf16_t* arow = h0 + ((size_t)(T_SZ - 1) * B_SZ + bt * 16 + l15) * 512;
  f32x4 acc[4] = {{0,0,0,0},{0,0,0,0},{0,0,0,0},{0,0,0,0}};
#pragma unroll 4
  for (int kt = 0; kt < 16; ++kt) {
    bf16x8 a = *(const bf16x8*)(arow + kt * 32 + quad * 8);
#pragma unroll
    for (int g = 0; g < 4; ++g) {
      bf16x8 w = *(const bf16x8*)(wih_r + (size_t)(g * H_SZ + c0 + l15) * 512 + kt * 32 + quad * 8);
      acc[g] = MFMA(a, w, acc[g]);
    }
  }
  const int j = c0 + l15;
  const float bi = bias_r[j], bg = bias_r[2 * H_SZ + j], bo = bias_r[3 * H_SZ + j];
#pragma unroll
  for (int r = 0; r < 4; ++r) {
    const int row = bt * 16 + quad * 4 + r;
    float iv = sigm(acc[0][r] + bi);
    float gv = tanhx(acc[2][r] + bg);
    float ov = sigm(acc[3][r] + bo);
    float cn = iv * gv;  // f*0 + i*g
    h1b[(size_t)row * H_SZ + j] = (bf16_t)(ov * tanhx(cn));
  }
}

// ---------------------------------------------------------------------------
// prep + head
// ---------------------------------------------------------------------------
__global__ void k_cvt4(const float* __restrict__ s, bf16_t* __restrict__ d, int n4) {
  int i = blockIdx.x * 256 + threadIdx.x;
  if (i < n4) {
    float4 v = ((const float4*)s)[i];
    bf16x4 o; o[0] = (bf16_t)v.x; o[1] = (bf16_t)v.y; o[2] = (bf16_t)v.z; o[3] = (bf16_t)v.w;
    ((bf16x4*)d)[i] = o;
  }
}
__global__ void k_split(const float* __restrict__ s, bf16_t* __restrict__ hi,
                        bf16_t* __restrict__ lo, int n) {
  int i = blockIdx.x * 256 + threadIdx.x;
  if (i < n) {
    float v = s[i];
    bf16_t h = (bf16_t)v;
    hi[i] = h;
    lo[i] = (bf16_t)(v - (float)h);
  }
}
__global__ void k_bias(const float* __restrict__ a, const float* __restrict__ b,
                       float* __restrict__ d, int n) {
  int i = blockIdx.x * 256 + threadIdx.x;
  if (i < n) d[i] = a[i] + b[i];
}
__global__ void k_fill4(uint4* __restrict__ p, int n) {
  int i = blockIdx.x * 256 + threadIdx.x;
  if (i < n) p[i] = make_uint4(SENT32, SENT32, SENT32, SENT32);
}
__global__ void k_fc(const bf16_t* __restrict__ hf, const bf16_t* __restrict__ hb,
                     const float* __restrict__ fw, const float* __restrict__ fb,
                     float* __restrict__ out) {
  int b = threadIdx.x;
  float s = fb[0];
  const bf16_t* pf = hf + (size_t)b * H_SZ;
  const bf16_t* pb = hb + (size_t)b * H_SZ;
  for (int j = 0; j < H_SZ; ++j) s += fw[j] * (float)pf[j];
  for (int j = 0; j < H_SZ; ++j) s += fw[H_SZ + j] * (float)pb[j];
  out[b] = s;
}

extern "C" void kernel_launch(void* const* d_in, const int* in_sizes, int n_in,
                              void* d_out, int out_size, void* d_ws, size_t ws_size,
                              hipStream_t stream) {
  (void)in_sizes; (void)n_in; (void)out_size; (void)ws_size;
  const float* x      = (const float*)d_in[0];
  const float* wih[4] = {(const float*)d_in[1], (const float*)d_in[5],
                         (const float*)d_in[9], (const float*)d_in[13]};
  const float* whh[4] = {(const float*)d_in[2], (const float*)d_in[6],
                         (const float*)d_in[10], (const float*)d_in[14]};
  const float* bih[4] = {(const float*)d_in[3], (const float*)d_in[7],
                         (const float*)d_in[11], (const float*)d_in[15]};
  const float* bhh[4] = {(const float*)d_in[4], (const float*)d_in[8],
                         (const float*)d_in[12], (const float*)d_in[16]};
  const float* fcw = (const float*)d_in[17];
  const float* fcb = (const float*)d_in[18];
  float* out = (float*)d_out;

  char* p = (char*)d_ws;
  auto take = [&](size_t bytes) { char* r = p; p += (bytes + 255) & ~(size_t)255; return r; };
  const int KinL[4] = {64, 64, 512, 512};  // l0f, l0b, l1f, l1r
  bf16_t* wihb[4]; float* biasc[4]; bf16_t* whhhi[3]; bf16_t* whhlo[3];
  for (int k = 0; k < 4; ++k) {
    wihb[k]  = (bf16_t*)take((size_t)1024 * KinL[k] * 2);
    biasc[k] = (float*)take(1024 * 4);
  }
  for (int k = 0; k < 3; ++k) {
    whhhi[k] = (bf16_t*)take((size_t)1024 * 256 * 2);
    whhlo[k] = (bf16_t*)take((size_t)1024 * 256 * 2);
  }
  bf16_t* xbf = (bf16_t*)take((size_t)B_SZ * T_SZ * 64 * 2);
  bf16_t* h1f = (bf16_t*)take((size_t)B_SZ * H_SZ * 2);
  bf16_t* h1b = (bf16_t*)take((size_t)B_SZ * H_SZ * 2);
  // sentinel-filled region: h0 (128 MiB) + hg1 (64 MiB), contiguous
  char* sbeg = p;
  bf16_t* h0  = (bf16_t*)take((size_t)T_SZ * B_SZ * 512 * 2);       // 128 MiB
  bf16_t* hg1 = (bf16_t*)take((size_t)16 * T_SZ * 4096 * 2);        // 64 MiB
  size_t sbytes = (size_t)(p - sbeg);

  // ---- prep ----
  k_cvt4<<<dim3(8192), 256, 0, stream>>>(x, xbf, (B_SZ * T_SZ * 64) / 4);
  for (int k = 0; k < 4; ++k) {
    k_cvt4<<<dim3((1024 * KinL[k] / 4 + 255) / 256), 256, 0, stream>>>(
        wih[k], wihb[k], 1024 * KinL[k] / 4);
    k_bias<<<dim3(4), 256, 0, stream>>>(bih[k], bhh[k], biasc[k], 1024);
  }
  for (int k = 0; k < 3; ++k)
    k_split<<<dim3(1024), 256, 0, stream>>>(whh[k], whhhi[k], whhlo[k], 1024 * 256);
  {
    int n4 = (int)(sbytes / 16);   // NaN-sentinel fill (flag-in-data protocol)
    k_fill4<<<dim3((n4 + 255) / 256), 256, 0, stream>>>((uint4*)sbeg, n4);
  }

  // ---- scans ----
  l0_scan<<<dim3(128), 256, 0, stream>>>(
      xbf, wihb[0], whhhi[0], whhlo[0], biasc[0],
           wihb[1], whhhi[1], whhlo[1], biasc[1], h0);
  l1_scan<<<dim3(128), 512, 0, stream>>>(
      h0, wihb[2], whhhi[2], whhlo[2], biasc[2], h1f, hg1);
  l1b_step<<<dim3(64), 256, 0, stream>>>(h0, wihb[3], biasc[3], h1b);

  k_fc<<<dim3(1), 256, 0, stream>>>(h1f, h1b, fcw, fcb, out);
}

// Round 9
// 2015.429 us; speedup vs baseline: 1.6421x; 1.6421x over previous
//
#include <hip/hip_runtime.h>

typedef __bf16 bf16_t;
typedef bf16_t bf16x8 __attribute__((ext_vector_type(8)));
typedef bf16_t bf16x4 __attribute__((ext_vector_type(4)));
typedef float f32x4 __attribute__((ext_vector_type(4)));

#define B_SZ 256
#define T_SZ 512
#define H_SZ 256
#define SCOPE_AGENT __HIP_MEMORY_SCOPE_AGENT
#define SENT32 0x7FC17FC1u   // two bf16 NaNs; produced h is always finite

__device__ __forceinline__ float sigm(float x) { return 1.f / (1.f + __expf(-x)); }
__device__ __forceinline__ float tanhx(float x) {
  x = fminf(fmaxf(x, -15.f), 15.f);
  float e = __expf(-2.f * x);
  return (1.f - e) / (1.f + e);
}
__device__ __forceinline__ uint32_t pack_bf16x2(float a, float b) {
  union { bf16_t h[2]; uint32_t u; } v;
  v.h[0] = (bf16_t)a; v.h[1] = (bf16_t)b; return v.u;
}
__device__ __forceinline__ void st32_agent(uint32_t* p, uint32_t v) {
  __hip_atomic_store(p, v, __ATOMIC_RELAXED, SCOPE_AGENT);
}
__device__ __forceinline__ uint64_t ld64_agent(const uint64_t* p) {
  return __hip_atomic_load(p, __ATOMIC_RELAXED, SCOPE_AGENT);
}
__device__ __forceinline__ bool okv(uint64_t v) {
  return ((uint32_t)v != SENT32) & ((uint32_t)(v >> 32) != SENT32);
}
#define MFMA(a, b, c) __builtin_amdgcn_mfma_f32_16x16x32_bf16((a), (b), (c), 0, 0, 0)

// ---------------------------------------------------------------------------
// Layer 0 scan — R5 form (measured ~800 µs). 256 blocks = 2 dir x 16 bt x
// 8 ct with ct = id & 7 -> the 8 group-siblings SPREAD across 8 XCDs
// (8 parallel L3 fabric paths for the exchange; same-XCD concentration
// measurably serializes the coherence-point traffic). 256 threads (4 waves,
// 2 N-tiles each). Weights register-resident. Flag-in-data exchange on
// h0[t] (NaN sentinel), relaxed agent ops, no fences.
// ---------------------------------------------------------------------------
__global__ __launch_bounds__(256, 1) void l0_scan(
    const bf16_t* __restrict__ xbf,
    const bf16_t* __restrict__ wih_f, const bf16_t* __restrict__ whhhi_f,
    const bf16_t* __restrict__ whhlo_f, const float* __restrict__ bias_f,
    const bf16_t* __restrict__ wih_b, const bf16_t* __restrict__ whhhi_b,
    const bf16_t* __restrict__ whhlo_b, const float* __restrict__ bias_b,
    bf16_t* __restrict__ h0) {
  const int id = blockIdx.x;
  const int dir = id >> 7, bt = (id >> 3) & 15, ct = id & 7;  // XCD-spread
  const bf16_t* __restrict__ wih  = dir ? wih_b : wih_f;
  const bf16_t* __restrict__ whhh = dir ? whhhi_b : whhhi_f;
  const bf16_t* __restrict__ whhl = dir ? whhlo_b : whhlo_f;
  const float*  __restrict__ bias = dir ? bias_b : bias_f;

  const int tid = threadIdx.x;
  const int lane = tid & 63, wv = tid >> 6, l15 = lane & 15, quad = lane >> 4;
  const int b0 = bt * 16;

  __shared__ bf16_t hbl[16][264];   // staged h_prev (528B stride, 16B-aligned)
  __shared__ float  gl[16][132];    // gate pre-acts

  // ---- register-resident weight fragments (loaded once) ----
  bf16x8 wfi[2][2], wfh[2][8], wfl[2][8];
#pragma unroll
  for (int p = 0; p < 2; ++p) {
    const int gc = (wv * 2 + p) * 16 + l15;          // gate-col 0..127
    const int row = (gc >> 5) * H_SZ + ct * 32 + (gc & 31);
#pragma unroll
    for (int kt = 0; kt < 2; ++kt)
      wfi[p][kt] = *(const bf16x8*)(wih + (size_t)row * 64 + kt * 32 + quad * 8);
#pragma unroll
    for (int kt = 0; kt < 8; ++kt) {
      wfh[p][kt] = *(const bf16x8*)(whhh + (size_t)row * H_SZ + kt * 32 + quad * 8);
      wfl[p][kt] = *(const bf16x8*)(whhl + (size_t)row * H_SZ + kt * 32 + quad * 8);
    }
  }
  const int erow = tid >> 4, ecol = 2 * (tid & 15);
  const int gj = ct * 32 + ecol;
  float bia[4][2];
#pragma unroll
  for (int gg = 0; gg < 4; ++gg) {
    bia[gg][0] = bias[gg * H_SZ + gj];
    bia[gg][1] = bias[gg * H_SZ + gj + 1];
  }
  float2 c2 = {0.f, 0.f};
  const bf16_t* xrow = xbf + (size_t)(b0 + l15) * T_SZ * 64;
  // poll/stage ownership: row tid>>4, 4 u64 each (8 KB tile over 256 thr)
  const int prow = tid >> 4, pcq = (tid & 15) * 4;

  for (int s = 0; s < T_SZ; ++s) {
    const int t = dir ? (T_SZ - 1 - s) : s;
    // ---- input projection (independent of recurrence -> before poll) ----
    f32x4 acc0 = {0.f, 0.f, 0.f, 0.f}, acc1 = {0.f, 0.f, 0.f, 0.f};
#pragma unroll
    for (int kt = 0; kt < 2; ++kt) {
      bf16x8 xa = *(const bf16x8*)(xrow + t * 64 + kt * 32 + quad * 8);
      acc0 = MFMA(xa, wfi[0][kt], acc0);
      acc1 = MFMA(xa, wfi[1][kt], acc1);
    }
    if (s == 0) {
      for (int i = tid; i < 16 * 264 / 2; i += 256) ((uint32_t*)hbl)[i] = 0u;
    } else {
      const int tp = dir ? (t + 1) : (t - 1);     // previous step's t
      const uint64_t* src =
          (const uint64_t*)(h0 + ((size_t)tp * B_SZ + b0 + prow) * 512 + dir * H_SZ) + pcq;
      uint64_t v0, v1, v2, v3;
      for (;;) {
        v0 = ld64_agent(src);     v1 = ld64_agent(src + 1);
        v2 = ld64_agent(src + 2); v3 = ld64_agent(src + 3);
        if (okv(v0) && okv(v1) && okv(v2) && okv(v3)) break;
      }
      uint64_t* dst = (uint64_t*)&hbl[prow][pcq * 4];
      dst[0] = v0; dst[1] = v1; dst[2] = v2; dst[3] = v3;
    }
    __syncthreads();
    // ---- recurrent MFMAs (weights in registers, A from LDS) ----
#pragma unroll
    for (int kt = 0; kt < 8; ++kt) {
      bf16x8 ha = *(const bf16x8*)&hbl[l15][kt * 32 + quad * 8];
      acc0 = MFMA(ha, wfh[0][kt], acc0);
      acc0 = MFMA(ha, wfl[0][kt], acc0);
      acc1 = MFMA(ha, wfh[1][kt], acc1);
      acc1 = MFMA(ha, wfl[1][kt], acc1);
    }
    // ---- gates -> LDS (C/D layout: col=lane&15, row=quad*4+r) ----
#pragma unroll
    for (int r = 0; r < 4; ++r) {
      gl[quad * 4 + r][(wv * 2 + 0) * 16 + l15] = acc0[r];
      gl[quad * 4 + r][(wv * 2 + 1) * 16 + l15] = acc1[r];
    }
    __syncthreads();
    // ---- lane-owned gate combine; h store IS the exchange publish ----
    {
      float hv[2];
#pragma unroll
      for (int u = 0; u < 2; ++u) {
        float iv = sigm(gl[erow][0 * 32 + ecol + u] + bia[0][u]);
        float fv = sigm(gl[erow][1 * 32 + ecol + u] + bia[1][u]);
        float gv = tanhx(gl[erow][2 * 32 + ecol + u] + bia[2][u]);
        float ov = sigm(gl[erow][3 * 32 + ecol + u] + bia[3][u]);
        float cp = u ? c2.y : c2.x;
        float cn = fv * cp + iv * gv;
        if (u) c2.y = cn; else c2.x = cn;
        hv[u] = ov * tanhx(cn);
      }
      st32_agent((uint32_t*)(h0 + ((size_t)t * B_SZ + b0 + erow) * 512 + dir * H_SZ + gj),
                 pack_bf16x2(hv[0], hv[1]));
    }
  }
}

// ---------------------------------------------------------------------------
// Layer 1 forward scan — R6 form (measured ~690 µs). 128 blocks
// (ct = id>>4 -> bt-siblings share an XCD: dedups the CACHED h0 prefetch in
// that XCD's L2), 512 threads (8 waves). Prefetch global loads issue at loop
// top; their ds_write is deferred past the poll so h0 L3 latency hides
// inside the exchange wait.
// ---------------------------------------------------------------------------
__global__ __launch_bounds__(512, 2) void l1_scan(
    const bf16_t* __restrict__ h0,
    const bf16_t* __restrict__ wih, const bf16_t* __restrict__ whhh,
    const bf16_t* __restrict__ whhl, const float* __restrict__ bias,
    bf16_t* __restrict__ h1f, bf16_t* __restrict__ hg1) {
  const int id = blockIdx.x;
  const int ct = id >> 4, bt = id & 15;       // XCD-locality swizzle
  bf16_t* hgs = hg1 + (size_t)bt * T_SZ * 4096;   // [s][16][256]

  const int tid = threadIdx.x;
  const int lane = tid & 63, wv = tid >> 6, l15 = lane & 15, quad = lane >> 4;
  const int b0 = bt * 16;

  __shared__ bf16_t ibl[2][16][520];
  __shared__ bf16_t hbl[16][264];
  __shared__ float  gl[16][132];

  const int gc = wv * 16 + l15;
  const int row = (gc >> 5) * H_SZ + ct * 32 + (gc & 31);
  bf16x8 wfi[16], wfh[8], wfl[8];
#pragma unroll
  for (int kt = 0; kt < 16; ++kt)
    wfi[kt] = *(const bf16x8*)(wih + (size_t)row * 512 + kt * 32 + quad * 8);
#pragma unroll
  for (int kt = 0; kt < 8; ++kt) {
    wfh[kt] = *(const bf16x8*)(whhh + (size_t)row * H_SZ + kt * 32 + quad * 8);
    wfl[kt] = *(const bf16x8*)(whhl + (size_t)row * H_SZ + kt * 32 + quad * 8);
  }
  const int et = tid & 255;
  const int erow = et >> 4, ecol = 2 * (et & 15);
  const int gj = ct * 32 + ecol;
  float bia[4][2];
#pragma unroll
  for (int g = 0; g < 4; ++g) {
    bia[g][0] = bias[g * H_SZ + gj];
    bia[g][1] = bias[g * H_SZ + gj + 1];
  }
  float2 c2 = {0.f, 0.f};
  const int prow = tid >> 5, pcq = (tid & 31) * 2;   // poll ownership
  const int fr = tid >> 5, fcc = (tid & 31) * 16;    // prefetch ownership

  // stage ibl[0] <- h0[t=0]
  {
    const bf16_t* src = h0 + ((size_t)(b0 + fr)) * 512 + fcc;
    *(bf16x8*)&ibl[0][fr][fcc]     = *(const bf16x8*)(src);
    *(bf16x8*)&ibl[0][fr][fcc + 8] = *(const bf16x8*)(src + 8);
  }
  __syncthreads();

  for (int s = 0; s < T_SZ; ++s) {
    const int cur = s & 1, nxt = cur ^ 1;
    // issue next-tile global loads NOW; ds_write deferred past the poll
    bf16x8 pf0, pf1;
    if (s + 1 < T_SZ) {
      const bf16_t* src = h0 + ((size_t)(s + 1) * B_SZ + b0 + fr) * 512 + fcc;
      pf0 = *(const bf16x8*)(src);
      pf1 = *(const bf16x8*)(src + 8);
    }
    // ---- input projection before poll ----
    f32x4 acc = {0.f, 0.f, 0.f, 0.f};
#pragma unroll
    for (int kt = 0; kt < 16; ++kt) {
      bf16x8 a = *(const bf16x8*)&ibl[cur][l15][kt * 32 + quad * 8];
      acc = MFMA(a, wfi[kt], acc);
    }
    if (s == 0) {
      for (int i = tid; i < 16 * 264 / 2; i += 512) ((uint32_t*)hbl)[i] = 0u;
    } else {
      const uint64_t* src =
          (const uint64_t*)(hgs + (size_t)(s - 1) * 4096 + prow * H_SZ) + pcq;
      uint64_t v0, v1;
      for (;;) {
        v0 = ld64_agent(src); v1 = ld64_agent(src + 1);
        if (okv(v0) && okv(v1)) break;
      }
      uint64_t* dst = (uint64_t*)&hbl[prow][pcq * 4];
      dst[0] = v0; dst[1] = v1;
    }
    // deferred prefetch ds_write (load latency absorbed by the poll)
    if (s + 1 < T_SZ) {
      *(bf16x8*)&ibl[nxt][fr][fcc]     = pf0;
      *(bf16x8*)&ibl[nxt][fr][fcc + 8] = pf1;
    }
    __syncthreads();
#pragma unroll
    for (int kt = 0; kt < 8; ++kt) {
      bf16x8 ha = *(const bf16x8*)&hbl[l15][kt * 32 + quad * 8];
      acc = MFMA(ha, wfh[kt], acc);
      acc = MFMA(ha, wfl[kt], acc);
    }
#pragma unroll
    for (int r = 0; r < 4; ++r) gl[quad * 4 + r][wv * 16 + l15] = acc[r];
    __syncthreads();
    if (tid < 256) {
      float hv[2];
#pragma unroll
      for (int u = 0; u < 2; ++u) {
        float iv = sigm(gl[erow][0 * 32 + ecol + u] + bia[0][u]);
        float fv = sigm(gl[erow][1 * 32 + ecol + u] + bia[1][u]);
        float gv = tanhx(gl[erow][2 * 32 + ecol + u] + bia[2][u]);
        float ov = sigm(gl[erow][3 * 32 + ecol + u] + bia[3][u]);
        float cp = u ? c2.y : c2.x;
        float cn = fv * cp + iv * gv;
        if (u) c2.y = cn; else c2.x = cn;
        hv[u] = ov * tanhx(cn);
      }
      uint32_t pk = pack_bf16x2(hv[0], hv[1]);
      st32_agent((uint32_t*)(hgs + (size_t)s * 4096 + erow * H_SZ + gj), pk);
      if (s == T_SZ - 1)
        *(uint32_t*)(h1f + (size_t)(b0 + erow) * H_SZ + gj) = pk;
    }
  }
}

// ---------------------------------------------------------------------------
// Layer 1 reverse direction: output needs only t=T-1 = ONE step from zero
// state -> pure input projection + gate combine.
// ---------------------------------------------------------------------------
__global__ __launch_bounds__(256) void l1b_step(
    const bf16_t* __restrict__ h0, const bf16_t* __restrict__ wih_r,
    const float* __restrict__ bias_r, bf16_t* __restrict__ h1b) {
  const int bt = blockIdx.x >> 2, ct = blockIdx.x & 3;
  const int tid = threadIdx.x, lane = tid & 63, wv = tid >> 6;
  const int l15 = lane & 15, quad = lane >> 4;
  const int c0 = ct * 64 + wv * 16;
  const bf16_t* arow = h0 + ((size_t)(T_SZ - 1) * B_SZ + bt * 16 + l15) * 512;
  f32x4 acc[4] = {{0,0,0,0},{0,0,0,0},{0,0,0,0},{0,0,0,0}};
#pragma unroll 4
  for (int kt = 0; kt < 16; ++kt) {
    bf16x8 a = *(const bf16x8*)(arow + kt * 32 + quad * 8);
#pragma unroll
    for (int g = 0; g < 4; ++g) {
      bf16x8 w = *(const bf16x8*)(wih_r + (size_t)(g * H_SZ + c0 + l15) * 512 + kt * 32 + quad * 8);
      acc[g] = MFMA(a, w, acc[g]);
    }
  }
  const int j = c0 + l15;
  const float bi = bias_r[j], bg = bias_r[2 * H_SZ + j], bo = bias_r[3 * H_SZ + j];
#pragma unroll
  for (int r = 0; r < 4; ++r) {
    const int row = bt * 16 + quad * 4 + r;
    float iv = sigm(acc[0][r] + bi);
    float gv = tanhx(acc[2][r] + bg);
    float ov = sigm(acc[3][r] + bo);
    float cn = iv * gv;  // f*0 + i*g
    h1b[(size_t)row * H_SZ + j] = (bf16_t)(ov * tanhx(cn));
  }
}

// ---------------------------------------------------------------------------
// prep + head
// ---------------------------------------------------------------------------
__global__ void k_cvt4(const float* __restrict__ s, bf16_t* __restrict__ d, int n4) {
  int i = blockIdx.x * 256 + threadIdx.x;
  if (i < n4) {
    float4 v = ((const float4*)s)[i];
    bf16x4 o; o[0] = (bf16_t)v.x; o[1] = (bf16_t)v.y; o[2] = (bf16_t)v.z; o[3] = (bf16_t)v.w;
    ((bf16x4*)d)[i] = o;
  }
}
__global__ void k_split(const float* __restrict__ s, bf16_t* __restrict__ hi,
                        bf16_t* __restrict__ lo, int n) {
  int i = blockIdx.x * 256 + threadIdx.x;
  if (i < n) {
    float v = s[i];
    bf16_t h = (bf16_t)v;
    hi[i] = h;
    lo[i] = (bf16_t)(v - (float)h);
  }
}
__global__ void k_bias(const float* __restrict__ a, const float* __restrict__ b,
                       float* __restrict__ d, int n) {
  int i = blockIdx.x * 256 + threadIdx.x;
  if (i < n) d[i] = a[i] + b[i];
}
__global__ void k_fill4(uint4* __restrict__ p, int n) {
  int i = blockIdx.x * 256 + threadIdx.x;
  if (i < n) p[i] = make_uint4(SENT32, SENT32, SENT32, SENT32);
}
__global__ void k_fc(const bf16_t* __restrict__ hf, const bf16_t* __restrict__ hb,
                     const float* __restrict__ fw, const float* __restrict__ fb,
                     float* __restrict__ out) {
  int b = threadIdx.x;
  float s = fb[0];
  const bf16_t* pf = hf + (size_t)b * H_SZ;
  const bf16_t* pb = hb + (size_t)b * H_SZ;
  for (int j = 0; j < H_SZ; ++j) s += fw[j] * (float)pf[j];
  for (int j = 0; j < H_SZ; ++j) s += fw[H_SZ + j] * (float)pb[j];
  out[b] = s;
}

extern "C" void kernel_launch(void* const* d_in, const int* in_sizes, int n_in,
                              void* d_out, int out_size, void* d_ws, size_t ws_size,
                              hipStream_t stream) {
  (void)in_sizes; (void)n_in; (void)out_size; (void)ws_size;
  const float* x      = (const float*)d_in[0];
  const float* wih[4] = {(const float*)d_in[1], (const float*)d_in[5],
                         (const float*)d_in[9], (const float*)d_in[13]};
  const float* whh[4] = {(const float*)d_in[2], (const float*)d_in[6],
                         (const float*)d_in[10], (const float*)d_in[14]};
  const float* bih[4] = {(const float*)d_in[3], (const float*)d_in[7],
                         (const float*)d_in[11], (const float*)d_in[15]};
  const float* bhh[4] = {(const float*)d_in[4], (const float*)d_in[8],
                         (const float*)d_in[12], (const float*)d_in[16]};
  const float* fcw = (const float*)d_in[17];
  const float* fcb = (const float*)d_in[18];
  float* out = (float*)d_out;

  char* p = (char*)d_ws;
  auto take = [&](size_t bytes) { char* r = p; p += (bytes + 255) & ~(size_t)255; return r; };
  const int KinL[4] = {64, 64, 512, 512};  // l0f, l0b, l1f, l1r
  bf16_t* wihb[4]; float* biasc[4]; bf16_t* whhhi[3]; bf16_t* whhlo[3];
  for (int k = 0; k < 4; ++k) {
    wihb[k]  = (bf16_t*)take((size_t)1024 * KinL[k] * 2);
    biasc[k] = (float*)take(1024 * 4);
  }
  for (int k = 0; k < 3; ++k) {
    whhhi[k] = (bf16_t*)take((size_t)1024 * 256 * 2);
    whhlo[k] = (bf16_t*)take((size_t)1024 * 256 * 2);
  }
  bf16_t* xbf = (bf16_t*)take((size_t)B_SZ * T_SZ * 64 * 2);
  bf16_t* h1f = (bf16_t*)take((size_t)B_SZ * H_SZ * 2);
  bf16_t* h1b = (bf16_t*)take((size_t)B_SZ * H_SZ * 2);
  // sentinel-filled region: h0 (128 MiB) + hg1 (64 MiB), contiguous
  char* sbeg = p;
  bf16_t* h0  = (bf16_t*)take((size_t)T_SZ * B_SZ * 512 * 2);       // 128 MiB
  bf16_t* hg1 = (bf16_t*)take((size_t)16 * T_SZ * 4096 * 2);        // 64 MiB
  size_t sbytes = (size_t)(p - sbeg);

  // ---- prep ----
  k_cvt4<<<dim3(8192), 256, 0, stream>>>(x, xbf, (B_SZ * T_SZ * 64) / 4);
  for (int k = 0; k < 4; ++k) {
    k_cvt4<<<dim3((1024 * KinL[k] / 4 + 255) / 256), 256, 0, stream>>>(
        wih[k], wihb[k], 1024 * KinL[k] / 4);
    k_bias<<<dim3(4), 256, 0, stream>>>(bih[k], bhh[k], biasc[k], 1024);
  }
  for (int k = 0; k < 3; ++k)
    k_split<<<dim3(1024), 256, 0, stream>>>(whh[k], whhhi[k], whhlo[k], 1024 * 256);
  {
    int n4 = (int)(sbytes / 16);   // NaN-sentinel fill (flag-in-data protocol)
    k_fill4<<<dim3((n4 + 255) / 256), 256, 0, stream>>>((uint4*)sbeg, n4);
  }

  // ---- scans ----
  l0_scan<<<dim3(256), 256, 0, stream>>>(
      xbf, wihb[0], whhhi[0], whhlo[0], biasc[0],
           wihb[1], whhhi[1], whhlo[1], biasc[1], h0);
  l1_scan<<<dim3(128), 512, 0, stream>>>(
      h0, wihb[2], whhhi[2], whhlo[2], biasc[2], h1f, hg1);
  l1b_step<<<dim3(64), 256, 0, stream>>>(h0, wihb[3], biasc[3], h1b);

  k_fc<<<dim3(1), 256, 0, stream>>>(h1f, h1b, fcw, fcb, out);
}